// Round 4
// baseline (29.563 us; speedup 1.0000x reference)
//
#include <hip/hip_runtime.h>

#define N 4096
#define M 1024
#define D 64
#define MT 16                             // m-values per thread
#define SPLITS 32                         // N-chunks
#define ROWS_PER_BLOCK (N / SPLITS)       // 128
#define ROWS_PER_WAVE  (ROWS_PER_BLOCK/4) // 32
#define SITES (M * D)                     // 65536
#define K2_BLOCKS 256

// K1: partial min over an N-chunk for a 16-m tile, z_masked/z_copy fused.
// grid = 64 m-tiles * 32 splits = 2048 blocks (8 blocks/CU -> 8 waves/SIMD),
// 256 threads, lane = d. min_n (z-e)^2 = min_n (z^2-2ez) + e^2.
__global__ __launch_bounds__(256, 8) void k_minpart(const float* __restrict__ z,
                                                    const float* __restrict__ e,
                                                    const int* __restrict__ idx,
                                                    float* __restrict__ pout,
                                                    float* __restrict__ out,
                                                    int* __restrict__ counter) {
    const int bid = blockIdx.x;
    if (bid == 0 && threadIdx.x == 0) *counter = 0;   // reset for K2, every call

    // fused elementwise outputs: 128 elements per block
    if (threadIdx.x < 128) {
        const int i = bid * 128 + (int)threadIdx.x;
        const float zv = z[i];
        const int row = i >> 6, dd = i & 63;
        out[1 + i] = (dd < idx[row]) ? zv : 0.0f;   // z_masked
        out[1 + N * D + i] = zv;                    // z_copy
    }

    const int mt   = bid & 63;    // m-tile
    const int s    = bid >> 6;    // split
    const int lane = threadIdx.x & 63;
    const int w    = threadIdx.x >> 6;
    const int m0   = mt * MT;

    float n2e[MT];
#pragma unroll
    for (int j = 0; j < MT; ++j) n2e[j] = -2.0f * e[(m0 + j) * D + lane];

    float acc[MT];
#pragma unroll
    for (int j = 0; j < MT; ++j) acc[j] = 3.4e38f;

    const float* zp = z + (s * ROWS_PER_BLOCK + w * ROWS_PER_WAVE) * D + lane;
#pragma unroll 4
    for (int r = 0; r < ROWS_PER_WAVE; ++r) {
        const float zv = zp[r * D];
        const float z2 = zv * zv;
#pragma unroll
        for (int j = 0; j < MT; ++j)
            acc[j] = fminf(acc[j], fmaf(n2e[j], zv, z2));
    }

    __shared__ float lds[4][MT * 64];
#pragma unroll
    for (int j = 0; j < MT; ++j) lds[w][j * 64 + lane] = acc[j];
    __syncthreads();
    for (int p = threadIdx.x; p < MT * 64; p += 256) {
        const float v = fminf(fminf(lds[0][p], lds[1][p]),
                              fminf(lds[2][p], lds[3][p]));
        pout[s * SITES + m0 * 64 + p] = v;   // coalesced
    }
}

// K2: min over 32 splits + e^2, sum; deterministic last-block finish with
// PARALLEL coherent reads + fixed-order tree (no serial atomic chain).
__global__ __launch_bounds__(256) void k_minsum(const float* __restrict__ pout,
                                                const float* __restrict__ e,
                                                float* __restrict__ bsums,
                                                int* __restrict__ counter,
                                                float* __restrict__ out) {
    const int t = blockIdx.x * 256 + (int)threadIdx.x;  // 65536 threads, 1 site each
    float v = 3.4e38f;
#pragma unroll
    for (int si = 0; si < SPLITS; ++si)
        v = fminf(v, pout[si * SITES + t]);
    const float ev = e[t];
    float local = v + ev * ev;

#pragma unroll
    for (int off = 32; off > 0; off >>= 1)
        local += __shfl_down(local, off, 64);
    __shared__ float wsum[4];
    __shared__ int is_last;
    const int lane = threadIdx.x & 63, w = threadIdx.x >> 6;
    if (lane == 0) wsum[w] = local;
    __syncthreads();
    if (threadIdx.x == 0) {
        atomicExch(&bsums[blockIdx.x], (wsum[0] + wsum[1]) + (wsum[2] + wsum[3]));
        __threadfence();
        is_last = (atomicAdd(counter, 1) == K2_BLOCKS - 1);
    }
    __syncthreads();
    if (is_last) {
        __threadfence();
        // 256 parallel coherent reads, fixed-order deterministic reduce
        float x = atomicAdd(&bsums[threadIdx.x], 0.0f);
#pragma unroll
        for (int off = 32; off > 0; off >>= 1)
            x += __shfl_down(x, off, 64);
        __shared__ float fsum[4];
        if (lane == 0) fsum[w] = x;
        __syncthreads();
        if (threadIdx.x == 0)
            out[0] = ((fsum[0] + fsum[1]) + (fsum[2] + fsum[3])) * (1.0f / SITES);
    }
}

extern "C" void kernel_launch(void* const* d_in, const int* in_sizes, int n_in,
                              void* d_out, int out_size, void* d_ws, size_t ws_size,
                              hipStream_t stream) {
    const float* z   = (const float*)d_in[0];
    const float* e   = (const float*)d_in[1];
    const int*   idx = (const int*)d_in[2];
    float* out = (float*)d_out;

    float* pout    = (float*)d_ws;                       // 8 MB partials
    float* bsums   = (float*)d_ws + SPLITS * SITES;      // 256 floats
    int*   counter = (int*)(bsums + K2_BLOCKS);

    k_minpart<<<64 * SPLITS, 256, 0, stream>>>(z, e, idx, pout, out, counter);
    k_minsum<<<K2_BLOCKS, 256, 0, stream>>>(pout, e, bsums, counter, out);
}

// Round 5
// 26.974 us; speedup vs baseline: 1.0960x; 1.0960x over previous
//
#include <hip/hip_runtime.h>

#define N 4096
#define M 1024
#define D 64
#define MT 16                             // m-values per thread
#define SPLITS 16                         // N-chunks (R3 champion config)
#define ROWS_PER_BLOCK (N / SPLITS)       // 256
#define ROWS_PER_WAVE  (ROWS_PER_BLOCK/4) // 64
#define SITES (M * D)                     // 65536
#define K2_BLOCKS 256

// Register-only 3-input min (v_min3_f32). Same values as two fminf, 1 issue.
__device__ __forceinline__ float min3f(float a, float b, float c) {
    float d;
    asm("v_min3_f32 %0, %1, %2, %3" : "=v"(d) : "v"(a), "v"(b), "v"(c));
    return d;
}

// K1: partial min over an N-chunk for a 16-m tile, z_masked/z_copy fused.
// grid = 64 m-tiles * 16 splits = 1024 blocks, 256 threads, lane = d.
// min_n (z-e)^2 = min_n (z^2-2ez) + e^2; two rows per acc update via min3:
// 1 fma/site + 0.5 min3/site = 1.56 lane-ops/site (was 2.06).
__global__ __launch_bounds__(256) void k_minpart(const float* __restrict__ z,
                                                 const float* __restrict__ e,
                                                 const int* __restrict__ idx,
                                                 float* __restrict__ pout,
                                                 float* __restrict__ out,
                                                 int* __restrict__ counter) {
    const int bid = blockIdx.x;
    if (bid == 0 && threadIdx.x == 0) *counter = 0;   // reset for K2, every call

    // fused elementwise outputs: 256 elements per block
    {
        const int i = bid * 256 + (int)threadIdx.x;
        const float zv = z[i];
        const int row = i >> 6, dd = i & 63;
        out[1 + i] = (dd < idx[row]) ? zv : 0.0f;   // z_masked
        out[1 + N * D + i] = zv;                    // z_copy
    }

    const int mt   = bid & 63;    // m-tile
    const int s    = bid >> 6;    // split
    const int lane = threadIdx.x & 63;
    const int w    = threadIdx.x >> 6;
    const int m0   = mt * MT;

    float n2e[MT];
#pragma unroll
    for (int j = 0; j < MT; ++j) n2e[j] = -2.0f * e[(m0 + j) * D + lane];

    float acc[MT];
#pragma unroll
    for (int j = 0; j < MT; ++j) acc[j] = 3.4e38f;

    const float* zp = z + (s * ROWS_PER_BLOCK + w * ROWS_PER_WAVE) * D + lane;
#pragma unroll 4
    for (int rp = 0; rp < ROWS_PER_WAVE / 2; ++rp) {   // 32 row-pairs
        const float za = zp[(2 * rp) * D];
        const float zb = zp[(2 * rp + 1) * D];
        const float za2 = za * za;
        const float zb2 = zb * zb;
#pragma unroll
        for (int j = 0; j < MT; ++j) {
            const float t1 = fmaf(n2e[j], za, za2);
            const float t2 = fmaf(n2e[j], zb, zb2);
            acc[j] = min3f(acc[j], t1, t2);
        }
    }

    __shared__ float lds[4][MT * 64];
#pragma unroll
    for (int j = 0; j < MT; ++j) lds[w][j * 64 + lane] = acc[j];
    __syncthreads();
    for (int p = threadIdx.x; p < MT * 64; p += 256) {
        const float v = fminf(fminf(lds[0][p], lds[1][p]),
                              fminf(lds[2][p], lds[3][p]));
        pout[s * SITES + m0 * 64 + p] = v;   // coalesced
    }
}

// K2: min over 16 splits + e^2, sum; 256 blocks (all CUs), 1 site/thread.
// Deterministic last-block finish: 256 PARALLEL coherent reads + fixed tree.
__global__ __launch_bounds__(256) void k_minsum(const float* __restrict__ pout,
                                                const float* __restrict__ e,
                                                float* __restrict__ bsums,
                                                int* __restrict__ counter,
                                                float* __restrict__ out) {
    const int t = blockIdx.x * 256 + (int)threadIdx.x;  // 65536 threads, 1 site
    float p[SPLITS];
#pragma unroll
    for (int si = 0; si < SPLITS; ++si) p[si] = pout[si * SITES + t];
    float v = min3f(p[0], p[1], p[2]);
    v = min3f(v, p[3], p[4]);   v = min3f(v, p[5], p[6]);
    v = min3f(v, p[7], p[8]);   v = min3f(v, p[9], p[10]);
    v = min3f(v, p[11], p[12]); v = min3f(v, p[13], p[14]);
    v = fminf(v, p[15]);
    const float ev = e[t];
    float local = v + ev * ev;

#pragma unroll
    for (int off = 32; off > 0; off >>= 1)
        local += __shfl_down(local, off, 64);
    __shared__ float wsum[4];
    __shared__ int is_last;
    const int lane = threadIdx.x & 63, w = threadIdx.x >> 6;
    if (lane == 0) wsum[w] = local;
    __syncthreads();
    if (threadIdx.x == 0) {
        atomicExch(&bsums[blockIdx.x], (wsum[0] + wsum[1]) + (wsum[2] + wsum[3]));
        __threadfence();
        is_last = (atomicAdd(counter, 1) == K2_BLOCKS - 1);
    }
    __syncthreads();
    if (is_last) {
        __threadfence();
        float x = atomicAdd(&bsums[threadIdx.x], 0.0f);  // 256 parallel reads
#pragma unroll
        for (int off = 32; off > 0; off >>= 1)
            x += __shfl_down(x, off, 64);
        __shared__ float fsum[4];
        if (lane == 0) fsum[w] = x;
        __syncthreads();
        if (threadIdx.x == 0)
            out[0] = ((fsum[0] + fsum[1]) + (fsum[2] + fsum[3])) * (1.0f / SITES);
    }
}

extern "C" void kernel_launch(void* const* d_in, const int* in_sizes, int n_in,
                              void* d_out, int out_size, void* d_ws, size_t ws_size,
                              hipStream_t stream) {
    const float* z   = (const float*)d_in[0];
    const float* e   = (const float*)d_in[1];
    const int*   idx = (const int*)d_in[2];
    float* out = (float*)d_out;

    float* pout    = (float*)d_ws;                       // 4 MB partials
    float* bsums   = (float*)d_ws + SPLITS * SITES;      // 256 floats
    int*   counter = (int*)(bsums + K2_BLOCKS);

    k_minpart<<<64 * SPLITS, 256, 0, stream>>>(z, e, idx, pout, out, counter);
    k_minsum<<<K2_BLOCKS, 256, 0, stream>>>(pout, e, bsums, counter, out);
}

// Round 6
// 23.417 us; speedup vs baseline: 1.2625x; 1.1519x over previous
//
#include <hip/hip_runtime.h>

#define N 4096
#define M 1024
#define D 64
#define MT 16                             // m-values per thread
#define SPLITS 16                         // N-chunks (R3 champion config)
#define ROWS_PER_BLOCK (N / SPLITS)       // 256
#define ROWS_PER_WAVE  (ROWS_PER_BLOCK/4) // 64
#define SITES (M * D)                     // 65536
#define K2_BLOCKS 64

// Register-only 3-input min (v_min3_f32), minnum semantics = fminf twice.
__device__ __forceinline__ float min3f(float a, float b, float c) {
    float d;
    asm("v_min3_f32 %0, %1, %2, %3" : "=v"(d) : "v"(a), "v"(b), "v"(c));
    return d;
}

// K1: partial min over an N-chunk for a 16-m tile, z_masked/z_copy fused.
// grid = 64 m-tiles * 16 splits = 1024 blocks, 256 threads, lane = d.
// min_n (z-e)^2 = min_n (z^2-2ez) + e^2.
// Inner loop: 4-row batches -> 4 independent loads issued together (MLP),
// 4 fma + 2 min3 per 4 rows = 1.5 lane-ops/site.
__global__ __launch_bounds__(256) void k_minpart(const float* __restrict__ z,
                                                 const float* __restrict__ e,
                                                 const int* __restrict__ idx,
                                                 float* __restrict__ pout,
                                                 float* __restrict__ out,
                                                 int* __restrict__ counter) {
    const int bid = blockIdx.x;
    if (bid == 0 && threadIdx.x == 0) *counter = 0;   // reset for K2, every call

    // fused elementwise outputs: 256 elements per block
    {
        const int i = bid * 256 + (int)threadIdx.x;
        const float zv = z[i];
        const int row = i >> 6, dd = i & 63;
        out[1 + i] = (dd < idx[row]) ? zv : 0.0f;   // z_masked
        out[1 + N * D + i] = zv;                    // z_copy
    }

    const int mt   = bid & 63;    // m-tile
    const int s    = bid >> 6;    // split
    const int lane = threadIdx.x & 63;
    const int w    = threadIdx.x >> 6;
    const int m0   = mt * MT;

    float n2e[MT];
#pragma unroll
    for (int j = 0; j < MT; ++j) n2e[j] = -2.0f * e[(m0 + j) * D + lane];

    float acc[MT];
#pragma unroll
    for (int j = 0; j < MT; ++j) acc[j] = 3.4e38f;

    const float* zp = z + (s * ROWS_PER_BLOCK + w * ROWS_PER_WAVE) * D + lane;
#pragma unroll 4
    for (int r4 = 0; r4 < ROWS_PER_WAVE / 4; ++r4) {   // 16 batches of 4 rows
        const float za = zp[(4 * r4 + 0) * D];
        const float zb = zp[(4 * r4 + 1) * D];
        const float zc = zp[(4 * r4 + 2) * D];
        const float zd = zp[(4 * r4 + 3) * D];
        const float za2 = za * za, zb2 = zb * zb;
        const float zc2 = zc * zc, zd2 = zd * zd;
#pragma unroll
        for (int j = 0; j < MT; ++j) {
            const float t1 = fmaf(n2e[j], za, za2);
            const float t2 = fmaf(n2e[j], zb, zb2);
            const float t3 = fmaf(n2e[j], zc, zc2);
            const float t4 = fmaf(n2e[j], zd, zd2);
            acc[j] = min3f(acc[j], min3f(t1, t2, t3), t4);
        }
    }

    __shared__ float lds[4][MT * 64];
#pragma unroll
    for (int j = 0; j < MT; ++j) lds[w][j * 64 + lane] = acc[j];
    __syncthreads();
    for (int p = threadIdx.x; p < MT * 64; p += 256) {
        const float v = fminf(fminf(lds[0][p], lds[1][p]),
                              fminf(lds[2][p], lds[3][p]));
        pout[s * SITES + m0 * 64 + p] = v;   // coalesced
    }
}

// K2: EXACT R3-champion form. min over 16 splits + e^2, sum; 64 blocks,
// 4 sites/thread; deterministic last-block finish with 64 PARALLEL coherent
// reads + fixed-order shuffle tree.
__global__ __launch_bounds__(256) void k_minsum(const float* __restrict__ pout,
                                                const float* __restrict__ e,
                                                float* __restrict__ bsums,
                                                int* __restrict__ counter,
                                                float* __restrict__ out) {
    const int t = blockIdx.x * 256 + (int)threadIdx.x;  // 16384 threads
    float local = 0.0f;
#pragma unroll
    for (int k = 0; k < 4; ++k) {
        const int site = t + k * 16384;
        float v = 3.4e38f;
#pragma unroll
        for (int si = 0; si < SPLITS; ++si)
            v = fminf(v, pout[si * SITES + site]);
        const float ev = e[site];
        local += v + ev * ev;
    }
#pragma unroll
    for (int off = 32; off > 0; off >>= 1)
        local += __shfl_down(local, off, 64);
    __shared__ float wsum[4];
    __shared__ int is_last;
    const int lane = threadIdx.x & 63, w = threadIdx.x >> 6;
    if (lane == 0) wsum[w] = local;
    __syncthreads();
    if (threadIdx.x == 0) {
        atomicExch(&bsums[blockIdx.x], (wsum[0] + wsum[1]) + (wsum[2] + wsum[3]));
        __threadfence();
        is_last = (atomicAdd(counter, 1) == K2_BLOCKS - 1);
    }
    __syncthreads();
    if (is_last && threadIdx.x < 64) {
        __threadfence();
        float v = atomicAdd(&bsums[threadIdx.x], 0.0f);  // 64 parallel reads
#pragma unroll
        for (int off = 32; off > 0; off >>= 1)
            v += __shfl_down(v, off, 64);
        if (threadIdx.x == 0) out[0] = v * (1.0f / SITES);
    }
}

extern "C" void kernel_launch(void* const* d_in, const int* in_sizes, int n_in,
                              void* d_out, int out_size, void* d_ws, size_t ws_size,
                              hipStream_t stream) {
    const float* z   = (const float*)d_in[0];
    const float* e   = (const float*)d_in[1];
    const int*   idx = (const int*)d_in[2];
    float* out = (float*)d_out;

    float* pout    = (float*)d_ws;                       // 4 MB partials
    float* bsums   = (float*)d_ws + SPLITS * SITES;      // 64 floats
    int*   counter = (int*)(bsums + K2_BLOCKS);

    k_minpart<<<64 * SPLITS, 256, 0, stream>>>(z, e, idx, pout, out, counter);
    k_minsum<<<K2_BLOCKS, 256, 0, stream>>>(pout, e, bsums, counter, out);
}